// Round 5
// baseline (538.370 us; speedup 1.0000x reference)
//
#include <hip/hip_runtime.h>
#include <hip/hip_cooperative_groups.h>
#include <math.h>

namespace cg = cooperative_groups;

#define HH 721
#define WW 1440
#define HWV (HH*WW)        // 1038240
#define NB 16
#define NC 4
#define ND 256
#define NL 4
#define NQ (HWV/4)         // 259560 float4 quads per plane

#define PHI_F 1.61803398874989484820458683436564f

// ---- workspace layout (bytes) ----
#define WS_TBL 512                     // float[16*48]
#define WS_HNA 4096                    // float[16*12*256]
#define WS_HNB (4096 + NB*12*ND*4)     // float[16*12*256]

typedef float vfloat4 __attribute__((ext_vector_type(4)));

__constant__ float c_rx[12] = {-1.f, 1.f, -1.f, 1.f,  0.f, 0.f, 0.f, 0.f,
                               PHI_F, PHI_F, -PHI_F, -PHI_F};
__constant__ float c_ry[12] = {PHI_F, PHI_F, -PHI_F, -PHI_F, -1.f, 1.f, -1.f, 1.f,
                               0.f, 0.f, 0.f, 0.f};
__constant__ float c_rz[12] = {0.f, 0.f, 0.f, 0.f, PHI_F, PHI_F, -PHI_F, -PHI_F,
                               -1.f, 1.f, -1.f, 1.f};
// icosahedron adjacency (deg = 5 for every vertex)
__constant__ int c_nbr[12][5] = {
    {11, 5, 1, 7, 10}, {0, 5, 7, 9, 8}, {11, 10, 3, 4, 6}, {9, 4, 2, 6, 8},
    {5, 11, 3, 9, 2},  {0, 11, 1, 9, 4}, {10, 7, 3, 2, 8}, {0, 1, 10, 6, 8},
    {7, 1, 3, 6, 9},   {1, 5, 3, 4, 8},  {0, 7, 11, 2, 6}, {0, 5, 10, 4, 2}};

__device__ __forceinline__ void vert_latlon(int v, double* olat, double* olon) {
#pragma clang fp contract(off)
  const float P = PHI_F;
  float n = sqrtf(1.0f + P * P);
  float xf = c_rx[v] / n;
  float yf = c_ry[v] / n;
  float zf = c_rz[v] / n;
  *olat = asin((double)zf);
  *olon = atan2((double)yf, (double)xf);
}

__device__ __forceinline__ double grid_lat(int i) {
#pragma clang fp contract(off)
  if (i == 720) return M_PI / 2;
  double v = (double)i * (M_PI / 720.0);
  return v - M_PI / 2;
}

__device__ __forceinline__ double grid_lon(int j) {
#pragma clang fp contract(off)
  if (j == 1439) return M_PI;
  double v = (double)j * (2.0 * M_PI / 1439.0);
  return v - M_PI;
}

__device__ __forceinline__ double d2f(double lat, double lon, double vlat,
                                      double vlon) {
#pragma clang fp contract(off)
  double dlat = lat - vlat;
  double x = (lon - vlon) + M_PI;
  const double TP = 2.0 * M_PI;
  double r = (x < 0.0) ? (x + TP) : ((x >= TP) ? (x - TP) : x);
  double dlon = r - M_PI;
  return dlat * dlat + dlon * dlon;
}

// verbatim verified window-argmin for one vertex (same code/bits as before)
__device__ __forceinline__ int v2g_argmin(int n) {
  double vlat, vlon;
  vert_latlon(n, &vlat, &vlon);
  int i0 = (int)floor((vlat + M_PI / 2) / (M_PI / 720.0) + 0.5);
  int j0 = (int)floor((vlon + M_PI) / (2.0 * M_PI / 1439.0) + 0.5);
  int cand[11] = {0, 1, 2, 1437, 1438, 1439, j0 - 2, j0 - 1, j0, j0 + 1, j0 + 2};
  for (int a = 6; a < 11; a++) {
    if (cand[a] < 0) cand[a] = 0;
    if (cand[a] > 1439) cand[a] = 1439;
  }
  for (int a = 1; a < 11; a++) {
    int key = cand[a];
    int p = a - 1;
    while (p >= 0 && cand[p] > key) {
      cand[p + 1] = cand[p];
      p--;
    }
    cand[p + 1] = key;
  }
  double best = 1e300;
  int bi = 0;
  for (int ii = i0 - 2; ii <= i0 + 2; ii++) {
    if (ii < 0 || ii > 720) continue;
    double lat = grid_lat(ii);
    int prev = -1;
    for (int a = 0; a < 11; a++) {
      int j = cand[a];
      if (j == prev) continue;
      prev = j;
      double dq = d2f(lat, grid_lon(j), vlat, vlon);
      if (dq < best) {  // strict < == first-occurrence (verified semantics)
        best = dq;
        bi = ii * 1440 + j;
      }
    }
  }
  return bi;
}

// --- single cooperative GNN kernel: init + 4 layers + epilogue -------------
// 192 blocks = (batch b, node n), 256 threads = dim d. grid.sync() between
// layers replaces 5 dispatch boundaries. All per-output fmac chains are
// bit-identical to the verified chain version (same agg order, /5.0f,
// dd-ascending vfloat4-grouped GEMM, serial W_out epilogue).
__global__ __launch_bounds__(256) void gnn_fused(
    const float* __restrict__ x, const float* __restrict__ W_in,
    const float* __restrict__ b_in, const float* __restrict__ W_layers,
    const float* __restrict__ b_layers, const float* __restrict__ W_out,
    const float* __restrict__ b_out, char* __restrict__ ws) {
  __shared__ float s_f[4];
  __shared__ float s_agg[ND];
  __shared__ float s_hn[ND];
  __shared__ int s_k;
  const int blk = blockIdx.x;
  const int b = blk / 12, n = blk % 12;
  const int t = threadIdx.x;
  float* hnA = (float*)(ws + WS_HNA);
  float* hnB = (float*)(ws + WS_HNB);
  float* tbl = (float*)(ws + WS_TBL);

  if (t == 0) s_k = v2g_argmin(n);
  __syncthreads();
  if (t < 4) s_f[t] = x[(size_t)(b * NC + t) * HWV + s_k];
  __syncthreads();

  // hn0 = feats @ W_in + b_in (verified chain)
  {
    float s = b_in[t];
#pragma unroll
    for (int c = 0; c < 4; c++) s += s_f[c] * W_in[c * ND + t];
    hnA[(size_t)(b * 12 + n) * ND + t] = s;
  }
  cg::this_grid().sync();

  const float* hs = hnA;
  float* hd = hnB;
  for (int l = 0; l < NL; l++) {
    // agg: same neighbor order + /5.0f (bit-identical)
    float a = 0.f;
#pragma unroll
    for (int e = 0; e < 5; e++)
      a += hs[(size_t)(b * 12 + c_nbr[n][e]) * ND + t];
    s_agg[t] = a / 5.0f;
    float hold = hs[(size_t)(b * 12 + n) * ND + t];
    __syncthreads();

    // GEMM: same dd-ascending vfloat4-grouped fmac chain as verified
    float acc = 0.f;
    const float* W = W_layers + (size_t)l * ND * ND + t;
#pragma unroll 8
    for (int dd = 0; dd < ND; dd += 4) {
      vfloat4 a4 = *(const vfloat4*)&s_agg[dd];  // wave-uniform b128 broadcast
      float w0 = W[(size_t)(dd + 0) * ND];
      float w1 = W[(size_t)(dd + 1) * ND];
      float w2 = W[(size_t)(dd + 2) * ND];
      float w3 = W[(size_t)(dd + 3) * ND];
      acc += a4.x * w0; acc += a4.y * w1; acc += a4.z * w2; acc += a4.w * w3;
    }
    float u = acc + b_layers[l * ND + t];
    float hnew = hold + ((u > 0.f) ? u : 0.f);

    if (l < NL - 1) {
      hd[(size_t)(b * 12 + n) * ND + t] = hnew;
      cg::this_grid().sync();
      const float* tmp = hd;
      hd = (float*)hs;
      hs = tmp;
      __syncthreads();  // s_agg rewrite safety for next iteration
    } else {
      // fused epilogue: verified serial dd-loop, c = t
      s_hn[t] = hnew;
      __syncthreads();
      if (t < 4) {
        int c = t;
        float s = b_out[c];
        for (int dd = 0; dd < ND; dd++) s += s_hn[dd] * W_out[dd * 4 + c];
        tbl[b * 48 + c * 12 + n] = s;
      }
    }
  }
}

// --- kernel 2: fused nearest-vertex mapping + scatter-write ----------------
// Self-contained verified form (recomputes vlat/vlon per block; strict <,
// row-360 twin flip). Do not alter any arithmetic here.
__global__ __launch_bounds__(256) void scatter_kernel(
    const float* __restrict__ tbl_g, float* __restrict__ out) {
  __shared__ float s_tbl[NB * NC * 12];
  __shared__ double svlat[12], svlon[12];
  const int t = threadIdx.x;
  if (t < 12) {
    double a, o;
    vert_latlon(t, &a, &o);
    svlat[t] = a;
    svlon[t] = o;
  }
  for (int i = t; i < NB * NC * 12; i += 256) s_tbl[i] = tbl_g[i];
  __syncthreads();

  int q = blockIdx.x * 256 + t;
  if (q >= NQ) return;
  int h = q / 360;
  int w4 = (q - h * 360) * 4;

  int v[4];
#pragma unroll
  for (int s2 = 0; s2 < 4; s2++) {
    int kk = (w4 + s2) * 721 + h;  // reference's reshape(lon,lat).T scramble
    int i2 = kk / 1440;
    int j2 = kk - i2 * 1440;
    double lat = grid_lat(i2);
    double lon = grid_lon(j2);
    double best = 1e300;
    int bv = 0;
#pragma unroll
    for (int vv = 0; vv < 12; vv++) {
      double dd = d2f(lat, lon, svlat[vv], svlon[vv]);
      if (dd < best) {
        best = dd;
        bv = vv;
      }
    }
    // Row-360 twin flip (verified): equator crumb sign differs from XLA's
    // f32-native linspace -> flip 8<->9, 10<->11 on row 360.
    if (i2 == 360 && bv >= 8) bv ^= 1;
    v[s2] = bv;
  }

  vfloat4* out4 = (vfloat4*)out;
#pragma unroll
  for (int b = 0; b < NB; b++) {
#pragma unroll
    for (int c = 0; c < NC; c++) {
      const float* tb = &s_tbl[b * 48 + c * 12];
      vfloat4 val = {tb[v[0]], tb[v[1]], tb[v[2]], tb[v[3]]};
      __builtin_nontemporal_store(val, &out4[(size_t)(b * 4 + c) * NQ + q]);
    }
  }
}

extern "C" void kernel_launch(void* const* d_in, const int* in_sizes, int n_in,
                              void* d_out, int out_size, void* d_ws,
                              size_t ws_size, hipStream_t stream) {
  const float* x = (const float*)d_in[0];
  const float* W_in = (const float*)d_in[2];
  const float* b_in = (const float*)d_in[3];
  const float* W_layers = (const float*)d_in[4];
  const float* b_layers = (const float*)d_in[5];
  const float* W_out = (const float*)d_in[6];
  const float* b_out = (const float*)d_in[7];
  float* out = (float*)d_out;
  char* ws = (char*)d_ws;
  float* tbl = (float*)(ws + WS_TBL);

  void* args[] = {(void*)&x,        (void*)&W_in,  (void*)&b_in,
                  (void*)&W_layers, (void*)&b_layers, (void*)&W_out,
                  (void*)&b_out,    (void*)&ws};
  hipLaunchCooperativeKernel((const void*)gnn_fused, dim3(NB * 12), dim3(256),
                             args, 0, stream);

  int blocks = (NQ + 255) / 256;  // 1014
  scatter_kernel<<<blocks, 256, 0, stream>>>(tbl, out);
}